// Round 5
// baseline (320.614 us; speedup 1.0000x reference)
//
#include <hip/hip_runtime.h>

// Problem: x (32,4,512,512) fp32.
// reference = InstanceNorm( sum_j (2^j/15) * ((x * k_j + 1) * 0.5) )
// Collapses to: c = x * K (single 3x3 depthwise, zero pad, K entries sum to 0,
// center weight 1), then (c - mean_c) * rsqrt(var_c + 4e-5)
//
// R5: fused single kernel at FULL grid. R1 proved fused+flags correct but ran
// at 43% occupancy (1024 blocks = 4/CU cap) with seam-heavy DS loads. R4
// proved the cheap halo scheme (shuffles + 2 masked scalar edge loads) at
// ~48 VGPR. Combining: 2048 blocks x 256 thr (4 waves), 8 blocks/CU -> full
// 32-wave pool, wave = 16-row x 256-col strip, phase B re-reads the block's
// OWN slab (L1/L2-hot).
//   Phase A: conv-on-the-fly (s,ss) partial -> ws + release flag (agent).
//   Spin (bounded): wave 0 polls the plane's 16 flags; ON TIMEOUT the lane
//   recomputes the missing slab itself (scalar, never taken in practice) so
//   correctness never depends on dispatch order (G16).
//   Phase B: recompute conv, normalize, NT-store.
// R2 lesson: no min-waves launch_bounds (over-squeeze -> scratch spill).
// Host fallback: if ws_size < 24 KB the proven two-kernel path runs instead.

#define H 512
#define W 512
#define PLANES 128
#define NBLOCKS (PLANES * 16)   // 16 blocks/plane, 32 rows x 512 cols per block
#define MAGIC 0x5EED5EEDu
#define SPIN_LIMIT (1 << 16)

typedef float vfloat4 __attribute__((ext_vector_type(4)));

// combined kernel weights (x 1/30): [-8 -4 -2; -1 30 -1; -2 -4 -8]
#define WT0 (-8.0f/30.0f)
#define WT1 (-4.0f/30.0f)
#define WT2 (-2.0f/30.0f)
#define WM  (-1.0f/30.0f)

// Issue the loads for one row segment: coalesced float4 + masked edge
// scalars (lanes 0/63 only; those lines are cache-resident).
__device__ __forceinline__ void wissue(const float* __restrict__ rowp, int c0, int ch,
                                       int lane, bool valid,
                                       float4& m, float& lv, float& rv) {
    lv = 0.0f; rv = 0.0f;
    if (valid) {
        m = *reinterpret_cast<const float4*>(rowp + c0);
        if (lane == 0  && ch > 0)        lv = rowp[ch - 1];
        if (lane == 63 && ch + 256 < W)  rv = rowp[ch + 256];
    } else {
        m = make_float4(0.0f, 0.0f, 0.0f, 0.0f);
    }
}

// Extract halos at consumption: 2 shuffles, boundary lanes take the scalar.
__device__ __forceinline__ void wextract(const float4& m, float lv, float rv, int lane,
                                         float& l, float& r) {
    float fromL = __shfl_up(m.w, 1);
    float fromR = __shfl_down(m.x, 1);
    l = (lane == 0)  ? lv : fromL;
    r = (lane == 63) ? rv : fromR;
}

// 180-degree-symmetric kernel -> pair taps: 4 FMA + 4 ADD per output.
__device__ __forceinline__ float4 conv_row(float al, float4 a, float ar,
                                           float bl, float4 b, float br,
                                           float dl, float4 d, float dr) {
    float4 o;
    o.x = b.x + WT0*(al  + d.y) + WT1*(a.x + d.x) + WT2*(a.y + dl ) + WM*(bl  + b.y);
    o.y = b.y + WT0*(a.x + d.z) + WT1*(a.y + d.y) + WT2*(a.z + d.x) + WM*(b.x + b.z);
    o.z = b.z + WT0*(a.y + d.w) + WT1*(a.z + d.z) + WT2*(a.w + d.y) + WM*(b.y + b.w);
    o.w = b.w + WT0*(a.z + dr ) + WT1*(a.w + d.w) + WT2*(ar  + d.z) + WM*(b.z + br );
    return o;
}

// Scalar conv for the never-taken fallback path (dispatch-order safety).
__device__ float conv_px(const float* __restrict__ p, int r, int c) {
    auto v = [&](int rr, int cc) -> float {
        return (rr < 0 || rr >= H || cc < 0 || cc >= W) ? 0.0f : p[(size_t)rr * W + cc];
    };
    return v(r, c)
         + WT0 * (v(r-1, c-1) + v(r+1, c+1))
         + WT1 * (v(r-1, c  ) + v(r+1, c  ))
         + WT2 * (v(r-1, c+1) + v(r+1, c-1))
         + WM  * (v(r,   c-1) + v(r,   c+1));
}

__global__ __launch_bounds__(256) void fused_kernel(const float* __restrict__ x,
                                                    float* __restrict__ ws,
                                                    float* __restrict__ out) {
    const int tid   = threadIdx.x;
    const int wid   = tid >> 6;
    const int lane  = tid & 63;
    const int plane = blockIdx.x >> 4;
    const int slab  = blockIdx.x & 15;
    const int ch = (wid & 1) * 256;
    const int c0 = ch + lane * 4;
    const int r0 = slab * 32 + (wid >> 1) * 16;

    const float* __restrict__ p = x + (size_t)plane * H * W;
    unsigned int* flags = reinterpret_cast<unsigned int*>(ws + 2 * NBLOCKS);

    // ---------- Phase A: conv-on-the-fly stats (depth-2 pipelined) ----------
    float4 am, bm, cm, nm;
    float alv, arv, blv, brv, clv, crv, nlv, nrv;
    wissue(p + (size_t)(r0 - 1) * W, c0, ch, lane, r0 > 0, am, alv, arv);
    wissue(p + (size_t)r0 * W,       c0, ch, lane, true,   bm, blv, brv);
    wissue(p + (size_t)(r0 + 1) * W, c0, ch, lane, true,   cm, clv, crv);

    float al, ar, bl, br;
    wextract(am, alv, arv, lane, al, ar);
    wextract(bm, blv, brv, lane, bl, br);

    float s = 0.0f, ss = 0.0f;
    for (int r = r0; r < r0 + 16; ++r) {
        const bool nvalid = (r + 2 < H) && (r + 2 <= r0 + 16);
        wissue(p + (size_t)(r + 2) * W, c0, ch, lane, nvalid, nm, nlv, nrv);
        float cl, cr;
        wextract(cm, clv, crv, lane, cl, cr);
        float4 o = conv_row(al, am, ar, bl, bm, br, cl, cm, cr);
        s  += (o.x + o.y) + (o.z + o.w);
        ss += (o.x*o.x + o.y*o.y) + (o.z*o.z + o.w*o.w);
        am = bm; al = bl; ar = br;
        bm = cm; bl = cl; br = cr;
        cm = nm; clv = nlv; crv = nrv;
    }

    for (int off = 32; off > 0; off >>= 1) {
        s  += __shfl_down(s,  off);
        ss += __shfl_down(ss, off);
    }
    __shared__ float sh[8];
    if (lane == 0) { sh[wid * 2] = s; sh[wid * 2 + 1] = ss; }
    __syncthreads();

    // Publish partial FIRST (consumers are waiting), then prefetch.
    if (tid == 0) {
        ws[blockIdx.x * 2 + 0] = (sh[0] + sh[2]) + (sh[4] + sh[6]);
        ws[blockIdx.x * 2 + 1] = (sh[1] + sh[3]) + (sh[5] + sh[7]);
        __hip_atomic_store(&flags[blockIdx.x], MAGIC,
                           __ATOMIC_RELEASE, __HIP_MEMORY_SCOPE_AGENT);
    }

    // Phase-B prefetch of this block's OWN slab (L1/L2-hot from phase A):
    // independent of stats, hides latency under the spin.
    wissue(p + (size_t)(r0 - 1) * W, c0, ch, lane, r0 > 0, am, alv, arv);
    wissue(p + (size_t)r0 * W,       c0, ch, lane, true,   bm, blv, brv);
    wissue(p + (size_t)(r0 + 1) * W, c0, ch, lane, true,   cm, clv, crv);

    // ---------- gather plane stats: wave 0 polls the plane's 16 flags ------
    __shared__ float sb[2];
    if (tid < 64) {
        float s2 = 0.0f, ss2 = 0.0f;
        if (lane < 16) {
            const int idx = plane * 16 + lane;
            int spins = 0;
            bool got = false;
            while (spins < SPIN_LIMIT) {
                if (__hip_atomic_load(&flags[idx], __ATOMIC_ACQUIRE,
                                      __HIP_MEMORY_SCOPE_AGENT) == MAGIC) { got = true; break; }
                __builtin_amdgcn_s_sleep(2);
                ++spins;
            }
            if (got) {
                s2  = ws[idx * 2 + 0];
                ss2 = ws[idx * 2 + 1];
            } else {
                // Dispatch-order safety net: recompute the missing slab.
                const int rs = (idx & 15) * 32;
                for (int rr = rs; rr < rs + 32; ++rr)
                    for (int cc = 0; cc < W; ++cc) {
                        float v = conv_px(p, rr, cc);
                        s2 += v; ss2 += v * v;
                    }
            }
        }
        for (int off = 8; off > 0; off >>= 1) {
            s2  += __shfl_down(s2,  off);
            ss2 += __shfl_down(ss2, off);
        }
        if (lane == 0) { sb[0] = s2; sb[1] = ss2; }
    }
    __syncthreads();

    const float invN = 1.0f / (float)(H * W);
    const float mean = sb[0] * invN;
    const float var  = sb[1] * invN - mean * mean;
    const float rstd = rsqrtf(var + 4e-5f);

    // ---------- Phase B: recompute conv, normalize, NT store ----------
    float* __restrict__ q = out + (size_t)plane * H * W;

    wextract(am, alv, arv, lane, al, ar);
    wextract(bm, blv, brv, lane, bl, br);

    for (int r = r0; r < r0 + 16; ++r) {
        const bool nvalid = (r + 2 < H) && (r + 2 <= r0 + 16);
        wissue(p + (size_t)(r + 2) * W, c0, ch, lane, nvalid, nm, nlv, nrv);
        float cl, cr;
        wextract(cm, clv, crv, lane, cl, cr);
        float4 o = conv_row(al, am, ar, bl, bm, br, cl, cm, cr);
        vfloat4 y;
        y.x = (o.x - mean) * rstd;
        y.y = (o.y - mean) * rstd;
        y.z = (o.z - mean) * rstd;
        y.w = (o.w - mean) * rstd;
        __builtin_nontemporal_store(y, reinterpret_cast<vfloat4*>(q + (size_t)r * W + c0));
        am = bm; al = bl; ar = br;
        bm = cm; bl = cl; br = cr;
        cm = nm; clv = nlv; crv = nrv;
    }
}

// ---------------- two-kernel fallback (proven R4 path) ----------------

__global__ __launch_bounds__(256) void stats_kernel(const float* __restrict__ x,
                                                    float* __restrict__ ws) {
    const int tid   = threadIdx.x;
    const int wid   = tid >> 6;
    const int lane  = tid & 63;
    const int plane = blockIdx.x >> 4;
    const int slab  = blockIdx.x & 15;
    const int ch = (wid & 1) * 256;
    const int c0 = ch + lane * 4;
    const int r0 = slab * 32 + (wid >> 1) * 16;

    const float* __restrict__ p = x + (size_t)plane * H * W;

    float4 am, bm, cm, nm;
    float alv, arv, blv, brv, clv, crv, nlv, nrv;
    wissue(p + (size_t)(r0 - 1) * W, c0, ch, lane, r0 > 0, am, alv, arv);
    wissue(p + (size_t)r0 * W,       c0, ch, lane, true,   bm, blv, brv);
    wissue(p + (size_t)(r0 + 1) * W, c0, ch, lane, true,   cm, clv, crv);

    float al, ar, bl, br;
    wextract(am, alv, arv, lane, al, ar);
    wextract(bm, blv, brv, lane, bl, br);

    float s = 0.0f, ss = 0.0f;
    for (int r = r0; r < r0 + 16; ++r) {
        const bool nvalid = (r + 2 < H) && (r + 2 <= r0 + 16);
        wissue(p + (size_t)(r + 2) * W, c0, ch, lane, nvalid, nm, nlv, nrv);
        float cl, cr;
        wextract(cm, clv, crv, lane, cl, cr);
        float4 o = conv_row(al, am, ar, bl, bm, br, cl, cm, cr);
        s  += (o.x + o.y) + (o.z + o.w);
        ss += (o.x*o.x + o.y*o.y) + (o.z*o.z + o.w*o.w);
        am = bm; al = bl; ar = br;
        bm = cm; bl = cl; br = cr;
        cm = nm; clv = nlv; crv = nrv;
    }

    for (int off = 32; off > 0; off >>= 1) {
        s  += __shfl_down(s,  off);
        ss += __shfl_down(ss, off);
    }
    __shared__ float sh[8];
    if (lane == 0) { sh[wid * 2] = s; sh[wid * 2 + 1] = ss; }
    __syncthreads();
    if (tid == 0) {
        ws[blockIdx.x * 2 + 0] = (sh[0] + sh[2]) + (sh[4] + sh[6]);
        ws[blockIdx.x * 2 + 1] = (sh[1] + sh[3]) + (sh[5] + sh[7]);
    }
}

__global__ __launch_bounds__(256) void norm_kernel(const float* __restrict__ x,
                                                   const float* __restrict__ ws,
                                                   float* __restrict__ out) {
    const int tid   = threadIdx.x;
    const int wid   = tid >> 6;
    const int lane  = tid & 63;
    const int plane = blockIdx.x >> 4;
    const int slab  = blockIdx.x & 15;
    const int ch = (wid & 1) * 256;
    const int c0 = ch + lane * 4;
    const int r0 = slab * 32 + (wid >> 1) * 16;

    const float* __restrict__ p = x + (size_t)plane * H * W;

    float4 am, bm, cm, nm;
    float alv, arv, blv, brv, clv, crv, nlv, nrv;
    wissue(p + (size_t)(r0 - 1) * W, c0, ch, lane, r0 > 0, am, alv, arv);
    wissue(p + (size_t)r0 * W,       c0, ch, lane, true,   bm, blv, brv);
    wissue(p + (size_t)(r0 + 1) * W, c0, ch, lane, true,   cm, clv, crv);

    __shared__ float sb[2];
    if (tid < 64) {
        float s = 0.0f, ss = 0.0f;
        if (lane < 16) {
            s  = ws[(plane * 16 + lane) * 2 + 0];
            ss = ws[(plane * 16 + lane) * 2 + 1];
        }
        for (int off = 8; off > 0; off >>= 1) {
            s  += __shfl_down(s,  off);
            ss += __shfl_down(ss, off);
        }
        if (lane == 0) { sb[0] = s; sb[1] = ss; }
    }
    __syncthreads();
    const float invN = 1.0f / (float)(H * W);
    const float mean = sb[0] * invN;
    const float var  = sb[1] * invN - mean * mean;
    const float rstd = rsqrtf(var + 4e-5f);

    float al, ar, bl, br;
    wextract(am, alv, arv, lane, al, ar);
    wextract(bm, blv, brv, lane, bl, br);

    float* __restrict__ q = out + (size_t)plane * H * W;

    for (int r = r0; r < r0 + 16; ++r) {
        const bool nvalid = (r + 2 < H) && (r + 2 <= r0 + 16);
        wissue(p + (size_t)(r + 2) * W, c0, ch, lane, nvalid, nm, nlv, nrv);
        float cl, cr;
        wextract(cm, clv, crv, lane, cl, cr);
        float4 o = conv_row(al, am, ar, bl, bm, br, cl, cm, cr);
        vfloat4 y;
        y.x = (o.x - mean) * rstd;
        y.y = (o.y - mean) * rstd;
        y.z = (o.z - mean) * rstd;
        y.w = (o.w - mean) * rstd;
        __builtin_nontemporal_store(y, reinterpret_cast<vfloat4*>(q + (size_t)r * W + c0));
        am = bm; al = bl; ar = br;
        bm = cm; bl = cl; br = cr;
        cm = nm; clv = nlv; crv = nrv;
    }
}

extern "C" void kernel_launch(void* const* d_in, const int* in_sizes, int n_in,
                              void* d_out, int out_size, void* d_ws, size_t ws_size,
                              hipStream_t stream) {
    const float* x = (const float*)d_in[0];
    float* out = (float*)d_out;
    float* ws  = (float*)d_ws;

    if (ws_size >= (size_t)(2 * NBLOCKS * sizeof(float) + NBLOCKS * sizeof(unsigned int))) {
        fused_kernel<<<dim3(NBLOCKS), dim3(256), 0, stream>>>(x, ws, out);
    } else {
        stats_kernel<<<dim3(NBLOCKS), dim3(256), 0, stream>>>(x, ws);
        norm_kernel <<<dim3(NBLOCKS), dim3(256), 0, stream>>>(x, ws, out);
    }
}